// Round 8
// baseline (248.818 us; speedup 1.0000x reference)
//
#include <hip/hip_runtime.h>
#include <cstdint>
#include <cstddef>

// ---------------------------------------------------------------------------
// 2-layer GCN, round 22: full-row gather. r21 proved request count is the
// k_agg lever (4x64B -> 2x128B requests/edge = -10%, 236->228us total).
// This round: hb unified to row-major [N+1][128] bf16; each edge's 256B row
// gathered in ONE pass (16 lanes/node x dwordx4; 1 instr = 4 edges x 1KB).
// Requests/edge 2 -> 1; cols/cnt preload passes 2 -> 1. Same bytes, same
// instruction count. hb layout now == aggbuf layout (channel = nt*16+m).
// r15-r19: ILP/NT/warming/degree-sort all null or negative on k_agg.
//   k_cvt_w: zero cursor/ovf_cnt + dummy hb row + W1,W2 -> bf16 WT[N][K]
//   k_part / k_fill2: ELL-64 build (fill2 inits slab to dummy index N)
//   k_gemm_mfma<256,AF32>: hb = bf16((x@W1)*dinv[row]) row-major
//   k_agg<BF16OUT=1> -> aggbuf row-major bf16; k_gemm_mfma<128>; k_agg<0>
// ---------------------------------------------------------------------------

#define ELL_STRIDE 64
#define BCAP 8192
#define OVF_CAP 1024
#define PART_T 2048

typedef __attribute__((ext_vector_type(8))) short bf16x8;
typedef __attribute__((ext_vector_type(4))) float floatx4;

__device__ __forceinline__ unsigned short f2bf(float f) {
  unsigned int u = __float_as_uint(f);
  unsigned int r = (u + 0x7fffu + ((u >> 16) & 1u)) >> 16;   // RNE
  return (unsigned short)r;
}
__device__ __forceinline__ float2 bfpair(unsigned int p) {
  float2 r;
  r.x = __uint_as_float(p << 16);
  r.y = __uint_as_float(p & 0xffff0000u);
  return r;
}

// -------- zero workspace + dummy hb row + W -> bf16 transposed [128][K] ---
__global__ __launch_bounds__(256) void k_cvt_w(const float* __restrict__ W1,
                                               const float* __restrict__ W2,
                                               unsigned short* __restrict__ WT1,
                                               unsigned short* __restrict__ WT2,
                                               int* __restrict__ cursor,
                                               int* __restrict__ ovf_cnt,
                                               unsigned short* __restrict__ hb,
                                               int N, int NB) {
  int i = blockIdx.x * 256 + threadIdx.x;
  if (i < NB) cursor[i] = 0;
  if (i == NB) *ovf_cnt = 0;
  if (i < 128) {   // zero dummy row N: 128 shorts
    hb[(size_t)N * 128 + i] = 0;
  }
  if (i < 128 * 256) {                 // WT1[n][k] = W1[k][n], K=256
    int n = i >> 8, k = i & 255;
    WT1[i] = f2bf(W1[k * 128 + n]);
  } else if (i < 128 * 256 + 128 * 128) {
    int j = i - 128 * 256;             // WT2[n][k] = W2[k][n], K=128
    int n = j >> 7, k = j & 127;
    WT2[j] = f2bf(W2[k * 128 + n]);
  }
}

// ---------------- phase 1: bucket partition ----------------
__global__ __launch_bounds__(256) void k_part(const int* __restrict__ src,
                                              const int* __restrict__ dst,
                                              int* __restrict__ cursor,
                                              unsigned int* __restrict__ part,
                                              int* __restrict__ ovf_cnt,
                                              int* __restrict__ ovf,
                                              int E, int NB) {
  __shared__ unsigned int stage1[PART_T];
  __shared__ unsigned int stage2[PART_T];
  __shared__ int hist[512];
  __shared__ int base_g[512];
  __shared__ int base_l[512];
  __shared__ int cl[512];
  __shared__ int sc[256];
  const int tid = threadIdx.x;
  const int e0 = blockIdx.x * PART_T;
  int valid = E - e0; if (valid > PART_T) valid = PART_T;

  hist[tid] = 0; hist[tid + 256] = 0;
  cl[tid] = 0; cl[tid + 256] = 0;
  __syncthreads();
  for (int i = tid; i < valid; i += 256) {
    int e = e0 + i;
    unsigned int v = (unsigned int)(src[e] & 0xffff) | ((unsigned int)dst[e] << 16);
    stage1[i] = v;
    atomicAdd(&hist[(v >> 16) >> 7], 1);
  }
  __syncthreads();
  for (int b = tid; b < NB; b += 256) base_g[b] = atomicAdd(&cursor[b], hist[b]);
  int h0 = hist[2 * tid], h1 = hist[2 * tid + 1];
  int pv = h0 + h1;
  sc[tid] = pv;
  __syncthreads();
  #pragma unroll
  for (int off = 1; off < 256; off <<= 1) {
    int t = (tid >= off) ? sc[tid - off] : 0;
    __syncthreads();
    sc[tid] += t;
    __syncthreads();
  }
  int excl = sc[tid] - pv;
  base_l[2 * tid] = excl;
  base_l[2 * tid + 1] = excl + h0;
  __syncthreads();
  for (int i = tid; i < valid; i += 256) {
    unsigned int v = stage1[i];
    int b = (v >> 16) >> 7;
    int pos = base_l[b] + atomicAdd(&cl[b], 1);
    stage2[pos] = v;
  }
  __syncthreads();
  for (int i = tid; i < valid; i += 256) {
    unsigned int v = stage2[i];
    int b = (v >> 16) >> 7;
    int g = base_g[b] + (i - base_l[b]);
    if (g < BCAP) {
      part[(size_t)b * BCAP + g] = v;
    } else {
      int p = atomicAdd(ovf_cnt, 1);
      if (p < OVF_CAP) { ovf[2 * p] = (int)(v & 0xffffu); ovf[2 * p + 1] = (int)(v >> 16); }
    }
  }
}

// ---------------- phase 2: per-bucket ELL build in LDS ----------------
// slab pre-initialized to dummy index N -> unfilled slots gather a zero row.
__global__ __launch_bounds__(256) void k_fill2(const unsigned int* __restrict__ part,
                                               const int* __restrict__ cursor,
                                               unsigned short* __restrict__ col,
                                               int* __restrict__ cnt,
                                               float* __restrict__ dinv,
                                               int* __restrict__ ovf_cnt,
                                               int* __restrict__ ovf, int N) {
  __shared__ unsigned short slab[128 * ELL_STRIDE];  // 16 KB
  __shared__ int cl[128];
  const int tid = threadIdx.x;
  const int b = blockIdx.x;
  if (tid < 128) cl[tid] = 0;
  {
    unsigned int dpk = ((unsigned int)N << 16) | (unsigned int)N;
    unsigned int* s32 = (unsigned int*)slab;
    #pragma unroll
    for (int i = 0; i < (128 * ELL_STRIDE / 2) / 256; ++i)
      s32[i * 256 + tid] = dpk;
  }
  __syncthreads();
  int count = cursor[b]; if (count > BCAP) count = BCAP;
  const unsigned int* p = part + (size_t)b * BCAP;
  for (int i = tid; i < count; i += 256) {
    unsigned int v = p[i];
    int row = (v >> 16) & 127;
    int k = atomicAdd(&cl[row], 1);
    if (k < ELL_STRIDE) {
      slab[row * ELL_STRIDE + k] = (unsigned short)(v & 0xffffu);
    } else {
      int q = atomicAdd(ovf_cnt, 1);
      if (q < OVF_CAP) { ovf[2 * q] = (int)(v & 0xffffu); ovf[2 * q + 1] = (int)(v >> 16); }
    }
  }
  __syncthreads();
  uint4* d4 = (uint4*)(col + (size_t)b * 128 * ELL_STRIDE);
  const uint4* s4 = (const uint4*)slab;
  #pragma unroll
  for (int i = 0; i < (128 * ELL_STRIDE * 2) / (16 * 256); ++i)
    d4[i * 256 + tid] = s4[i * 256 + tid];
  if (tid < 128) {
    int node = b * 128 + tid;
    if (node < N) {
      int c = cl[tid];
      cnt[node] = c;
      dinv[node] = rsqrtf((float)c + 1.0f);
    }
  }
}

// ---------------- MFMA GEMM -> row-major hb [M+1][128] bf16 ---------------
// 512-thread block = 8 waves x 16-row strips = 128 rows. Whole WT staged in
// LDS once (rows padded +8 shorts), single barrier, then straight MFMA.
template <int K, bool AF32>
__global__ __launch_bounds__(512) void k_gemm_mfma(const void* __restrict__ Xv,
                                                   const unsigned short* __restrict__ WT,
                                                   const float* __restrict__ dinv,
                                                   unsigned short* __restrict__ hb,
                                                   int M) {
  constexpr int KP = K + 8;
  __shared__ unsigned short Bs[128 * KP];
  const int tid = threadIdx.x;
  const int wave = tid >> 6, lane = tid & 63;
  const int q = lane >> 4, m = lane & 15;
  const int row0 = blockIdx.x * 128 + wave * 16;   // M % 16 == 0
  const bool active = row0 < M;
  const int arow = row0 + m;

  for (int c = tid; c < 128 * (K / 8); c += 512) {
    int r = c / (K / 8), ko = (c % (K / 8)) * 8;
    *(uint4*)(Bs + r * KP + ko) = *(const uint4*)(WT + (size_t)r * K + ko);
  }

  bf16x8 af[K / 32];
  if (active) {
    #pragma unroll
    for (int ks = 0; ks < K / 32; ++ks) {
      const int k0 = ks * 32 + q * 8;
      if (AF32) {
        const float* X = (const float*)Xv;
        float4 a0 = *(const float4*)(X + (size_t)arow * K + k0);
        float4 a1 = *(const float4*)(X + (size_t)arow * K + k0 + 4);
        af[ks] = (bf16x8){(short)f2bf(a0.x), (short)f2bf(a0.y),
                          (short)f2bf(a0.z), (short)f2bf(a0.w),
                          (short)f2bf(a1.x), (short)f2bf(a1.y),
                          (short)f2bf(a1.z), (short)f2bf(a1.w)};
      } else {
        af[ks] = *(const bf16x8*)((const unsigned short*)Xv +
                                  (size_t)arow * K + k0);
      }
    }
  }
  __syncthreads();
  if (!active) return;

  floatx4 acc[8];
  #pragma unroll
  for (int nt = 0; nt < 8; ++nt) acc[nt] = (floatx4){0.f, 0.f, 0.f, 0.f};
  #pragma unroll
  for (int ks = 0; ks < K / 32; ++ks) {
    const int k0 = ks * 32 + q * 8;
    #pragma unroll
    for (int nt = 0; nt < 8; ++nt) {
      bf16x8 bf = *(const bf16x8*)(Bs + (nt * 16 + m) * KP + k0);
      acc[nt] = __builtin_amdgcn_mfma_f32_16x16x32_bf16(af[ks], bf, acc[nt], 0, 0, 0);
    }
  }
  #pragma unroll
  for (int r = 0; r < 4; ++r) {
    int grow = row0 + q * 4 + r;
    float di = dinv[grow];
    #pragma unroll
    for (int nt = 0; nt < 8; ++nt)
      hb[(size_t)grow * 128 + nt * 16 + m] = f2bf(acc[nt][r] * di);
  }
}

// ---------------- full-row ELL aggregate + bias + ReLU --------------------
// block = 16 nodes (4 waves x 4 nodes); 16 lanes/node x dwordx4 = 256B row
// (one edge gathered in a single pass; 1 VMEM instr = 4 edges x 1KB).
// Cols in LDS (72-short padded rows). No guards: ELL slots >= deg hold
// dummy node N whose hb row is zero.
template <bool BF16OUT>
__global__ __launch_bounds__(256) void k_agg(const uint4* __restrict__ hb4,
                                             const int* __restrict__ cnt,
                                             const unsigned short* __restrict__ col,
                                             const float* __restrict__ dinv,
                                             const int* __restrict__ ovf_cnt,
                                             const int* __restrict__ ovf,
                                             const float* __restrict__ bias,
                                             void* __restrict__ outv, int n) {
  __shared__ unsigned short cols[16][72];   // padded rows
  const int tid = threadIdx.x;
  const int nd0 = blockIdx.x * 16;
  if (tid < 128) {  // preload 16 x 64 cols (dummy-filled for OOB nodes)
    unsigned int dpk = ((unsigned int)n << 16) | (unsigned int)n;
    int node = tid >> 3, off = (tid & 7) * 8;
    uint4 v0 = make_uint4(dpk, dpk, dpk, dpk);
    if (nd0 + node < n)
      v0 = *(const uint4*)(col + (size_t)(nd0 + node) * ELL_STRIDE + off);
    *(uint4*)&cols[node][off] = v0;
  }
  __syncthreads();
  const int wave = tid >> 6, lane = tid & 63;
  const int nodeL = wave * 4 + (lane >> 4);
  const int q = lane & 15;                  // uint4 (8ch) within 128-ch row
  const int d = nd0 + nodeL;
  const bool valid = d < n;
  const uint4* slab = hb4;                  // [N+1][128] bf16 = 16 uint4/row
  const unsigned short* lc = cols[nodeL];

  float a0 = 0.f, a1 = 0.f, a2 = 0.f, a3 = 0.f;
  float a4 = 0.f, a5 = 0.f, a6 = 0.f, a7 = 0.f;
#define ADDP(P)                                                            \
  {                                                                        \
    float2 x0 = bfpair((P).x), x1 = bfpair((P).y);                         \
    float2 x2 = bfpair((P).z), x3 = bfpair((P).w);                         \
    a0 += x0.x; a1 += x0.y; a2 += x1.x; a3 += x1.y;                        \
    a4 += x2.x; a5 += x2.y; a6 += x3.x; a7 += x3.y;                        \
  }
  if (valid) {   // self-loop: hb pre-scaled by dinv -> hb[d]*dinv[d]
    uint4 p = slab[(size_t)d * 16 + q];
    ADDP(p)
  }
  int m = valid ? cnt[d] : 0; if (m > ELL_STRIDE) m = ELL_STRIDE;
  int mmax = m;
  #pragma unroll
  for (int s = 16; s < 64; s <<= 1) {
    int o = __shfl_xor(mmax, s);
    mmax = o > mmax ? o : mmax;
  }
  for (int k = 0; k < mmax; k += 8) {
    ushort4 ca = *(const ushort4*)(lc + k);
    ushort4 cb = *(const ushort4*)(lc + k + 4);
    uint4 p0 = slab[(size_t)ca.x * 16 + q];
    uint4 p1 = slab[(size_t)ca.y * 16 + q];
    uint4 p2 = slab[(size_t)ca.z * 16 + q];
    uint4 p3 = slab[(size_t)ca.w * 16 + q];
    uint4 p4 = slab[(size_t)cb.x * 16 + q];
    uint4 p5 = slab[(size_t)cb.y * 16 + q];
    uint4 p6 = slab[(size_t)cb.z * 16 + q];
    uint4 p7 = slab[(size_t)cb.w * 16 + q];
    ADDP(p0) ADDP(p1) ADDP(p2) ADDP(p3)
    ADDP(p4) ADDP(p5) ADDP(p6) ADDP(p7)
  }
  if (valid) {
    int V = *ovf_cnt; if (V > OVF_CAP) V = OVF_CAP;
    for (int j = 0; j < V; ++j) {
      if (ovf[2 * j + 1] == d) {
        uint4 p = slab[(size_t)ovf[2 * j] * 16 + q];
        ADDP(p)
      }
    }
  }
#undef ADDP
  if (!valid) return;
  float di = dinv[d];
  float4 b0 = *(const float4*)(bias + q * 8);
  float4 b1 = *(const float4*)(bias + q * 8 + 4);
  float r0 = fmaxf(di * a0 + b0.x, 0.f);
  float r1 = fmaxf(di * a1 + b0.y, 0.f);
  float r2 = fmaxf(di * a2 + b0.z, 0.f);
  float r3 = fmaxf(di * a3 + b0.w, 0.f);
  float r4 = fmaxf(di * a4 + b1.x, 0.f);
  float r5 = fmaxf(di * a5 + b1.y, 0.f);
  float r6 = fmaxf(di * a6 + b1.z, 0.f);
  float r7 = fmaxf(di * a7 + b1.w, 0.f);
  if (BF16OUT) {   // row-major [N][128] bf16 (true channel order) for gemm2
    uint4 pk;
    pk.x = (unsigned int)f2bf(r0) | ((unsigned int)f2bf(r1) << 16);
    pk.y = (unsigned int)f2bf(r2) | ((unsigned int)f2bf(r3) << 16);
    pk.z = (unsigned int)f2bf(r4) | ((unsigned int)f2bf(r5) << 16);
    pk.w = (unsigned int)f2bf(r6) | ((unsigned int)f2bf(r7) << 16);
    ((uint4*)outv)[(size_t)d * 16 + q] = pk;
  } else {
    float* o = (float*)outv + (size_t)d * 128 + q * 8;
    *(float4*)o = make_float4(r0, r1, r2, r3);
    *(float4*)(o + 4) = make_float4(r4, r5, r6, r7);
  }
}

// ---------------------------------------------------------------------------
extern "C" void kernel_launch(void* const* d_in, const int* in_sizes, int n_in,
                              void* d_out, int out_size, void* d_ws, size_t ws_size,
                              hipStream_t stream) {
  const float* x  = (const float*)d_in[0];
  const int*   ei = (const int*)d_in[1];
  const float* W1 = (const float*)d_in[2];
  const float* b1 = (const float*)d_in[3];
  const float* W2 = (const float*)d_in[4];
  const float* b2 = (const float*)d_in[5];
  float* out = (float*)d_out;

  const int IN_CH = 256;
  const int N = in_sizes[0] / IN_CH;   // 50000
  const int E = in_sizes[1] / 2;       // 1,600,000
  const int NB = (N + 127) >> 7;       // 391 buckets

  const int* src = ei;
  const int* dst = ei + E;

  char* ws = (char*)d_ws;
  size_t off = 0;
  auto carve = [&](size_t bytes) {
    void* p = ws + off;
    off += (bytes + 255) & ~(size_t)255;
    return p;
  };
  int*            cursor  = (int*)carve((size_t)NB * 4);
  int*            ovf_cnt = (int*)carve(4);
  int*            ovf     = (int*)carve((size_t)OVF_CAP * 2 * 4);
  int*            cnt     = (int*)carve((size_t)N * 4);
  float*          dinv    = (float*)carve((size_t)N * 4);
  unsigned short* col     = (unsigned short*)carve((size_t)N * ELL_STRIDE * 2); // 6.4MB
  unsigned short* hb      = (unsigned short*)carve((size_t)(N + 1) * 256);      // [N+1][128]
  unsigned short* WT1     = (unsigned short*)carve(128 * 256 * 2);
  unsigned short* WT2     = (unsigned short*)carve(128 * 128 * 2);
  // union: part (dead after k_fill2) aliases aggbuf (bf16, by k_agg#1)
  char*           unionp  = (char*)carve((size_t)NB * BCAP * 4);   // 12.8MB
  unsigned int*   part    = (unsigned int*)unionp;
  unsigned short* aggbuf  = (unsigned short*)unionp;               // [N][128] bf16

  k_cvt_w<<<(128 * 256 + 128 * 128 + 255) / 256, 256, 0, stream>>>(
      W1, W2, WT1, WT2, cursor, ovf_cnt, hb, N, NB);
  k_part <<<(E + PART_T - 1) / PART_T, 256, 0, stream>>>(src, dst, cursor, part,
                                                         ovf_cnt, ovf, E, NB);
  k_fill2<<<NB, 256, 0, stream>>>(part, cursor, col, cnt, dinv, ovf_cnt, ovf, N);

  int gblocks = (N + 127) / 128;         // 391
  int ablocks = (N + 15) / 16;           // 3125
  k_gemm_mfma<256, true ><<<gblocks, 512, 0, stream>>>(x, WT1, dinv, hb, N);
  k_agg<true ><<<ablocks, 256, 0, stream>>>((const uint4*)hb, cnt, col, dinv,
                                            ovf_cnt, ovf, b1, aggbuf, N);
  k_gemm_mfma<128, false><<<gblocks, 512, 0, stream>>>(aggbuf, WT2, dinv, hb, N);
  k_agg<false><<<ablocks, 256, 0, stream>>>((const uint4*)hb, cnt, col, dinv,
                                            ovf_cnt, ovf, b2, out, N);
}

// Round 9
// 236.694 us; speedup vs baseline: 1.0512x; 1.0512x over previous
//
#include <hip/hip_runtime.h>
#include <cstdint>
#include <cstddef>

// ---------------------------------------------------------------------------
// 2-layer GCN, round 23: r21 (best, 227.8us) + SRC-RADIX ELL slots.
// r21/r22 decomposed k_agg: segment count (128B req: -4us/disp) and per-XCD
// L2 residency (breaking it: +11us/disp). r21's 6.4MB/XCD slab > 4MB L2 ->
// residual LLC misses. This round: k_fill2 places edges at slot ~ src*64/N
// (CAS-probe, stable compact, dummy tail) -> gather loop sweeps the slab in
// ascending src; resident cohort touches a sliding ~1-2MB window that fits
// L2. k_agg byte-identical to r21.
// r15-r19: ILP/NT/warming/degree-sort null or negative on k_agg.
//   k_cvt_w: zero cursor/ovf_cnt + dummy hb rows + W1,W2 -> bf16 WT[N][K]
//   k_part / k_fill2: ELL-64 build, src-radix slot placement
//   k_gemm_mfma<256,AF32>: hb = bf16((x@W1)*dinv[row]) superchunk-major
//   k_agg<BF16OUT=1> -> aggbuf row-major bf16; k_gemm_mfma<128>; k_agg<0>
// ---------------------------------------------------------------------------

#define ELL_STRIDE 64
#define BCAP 8192
#define OVF_CAP 1024
#define PART_T 2048
#define SENT 0xffffffffu

typedef __attribute__((ext_vector_type(8))) short bf16x8;
typedef __attribute__((ext_vector_type(4))) float floatx4;

__device__ __forceinline__ unsigned short f2bf(float f) {
  unsigned int u = __float_as_uint(f);
  unsigned int r = (u + 0x7fffu + ((u >> 16) & 1u)) >> 16;   // RNE
  return (unsigned short)r;
}
__device__ __forceinline__ float2 bfpair(unsigned int p) {
  float2 r;
  r.x = __uint_as_float(p << 16);
  r.y = __uint_as_float(p & 0xffff0000u);
  return r;
}

// -------- zero workspace + dummy hb rows + W -> bf16 transposed [128][K] ---
__global__ __launch_bounds__(256) void k_cvt_w(const float* __restrict__ W1,
                                               const float* __restrict__ W2,
                                               unsigned short* __restrict__ WT1,
                                               unsigned short* __restrict__ WT2,
                                               int* __restrict__ cursor,
                                               int* __restrict__ ovf_cnt,
                                               unsigned short* __restrict__ hb,
                                               int N, int NB) {
  int i = blockIdx.x * 256 + threadIdx.x;
  if (i < NB) cursor[i] = 0;
  if (i == NB) *ovf_cnt = 0;
  if (i < 128) {   // zero dummy row N of each superchunk: 2 x 64 shorts
    int chunk = i >> 6, j = i & 63;
    hb[(size_t)chunk * (N + 1) * 64 + (size_t)N * 64 + j] = 0;
  }
  if (i < 128 * 256) {                 // WT1[n][k] = W1[k][n], K=256
    int n = i >> 8, k = i & 255;
    WT1[i] = f2bf(W1[k * 128 + n]);
  } else if (i < 128 * 256 + 128 * 128) {
    int j = i - 128 * 256;             // WT2[n][k] = W2[k][n], K=128
    int n = j >> 7, k = j & 127;
    WT2[j] = f2bf(W2[k * 128 + n]);
  }
}

// ---------------- phase 1: bucket partition ----------------
__global__ __launch_bounds__(256) void k_part(const int* __restrict__ src,
                                              const int* __restrict__ dst,
                                              int* __restrict__ cursor,
                                              unsigned int* __restrict__ part,
                                              int* __restrict__ ovf_cnt,
                                              int* __restrict__ ovf,
                                              int E, int NB) {
  __shared__ unsigned int stage1[PART_T];
  __shared__ unsigned int stage2[PART_T];
  __shared__ int hist[512];
  __shared__ int base_g[512];
  __shared__ int base_l[512];
  __shared__ int cl[512];
  __shared__ int sc[256];
  const int tid = threadIdx.x;
  const int e0 = blockIdx.x * PART_T;
  int valid = E - e0; if (valid > PART_T) valid = PART_T;

  hist[tid] = 0; hist[tid + 256] = 0;
  cl[tid] = 0; cl[tid + 256] = 0;
  __syncthreads();
  for (int i = tid; i < valid; i += 256) {
    int e = e0 + i;
    unsigned int v = (unsigned int)(src[e] & 0xffff) | ((unsigned int)dst[e] << 16);
    stage1[i] = v;
    atomicAdd(&hist[(v >> 16) >> 7], 1);
  }
  __syncthreads();
  for (int b = tid; b < NB; b += 256) base_g[b] = atomicAdd(&cursor[b], hist[b]);
  int h0 = hist[2 * tid], h1 = hist[2 * tid + 1];
  int pv = h0 + h1;
  sc[tid] = pv;
  __syncthreads();
  #pragma unroll
  for (int off = 1; off < 256; off <<= 1) {
    int t = (tid >= off) ? sc[tid - off] : 0;
    __syncthreads();
    sc[tid] += t;
    __syncthreads();
  }
  int excl = sc[tid] - pv;
  base_l[2 * tid] = excl;
  base_l[2 * tid + 1] = excl + h0;
  __syncthreads();
  for (int i = tid; i < valid; i += 256) {
    unsigned int v = stage1[i];
    int b = (v >> 16) >> 7;
    int pos = base_l[b] + atomicAdd(&cl[b], 1);
    stage2[pos] = v;
  }
  __syncthreads();
  for (int i = tid; i < valid; i += 256) {
    unsigned int v = stage2[i];
    int b = (v >> 16) >> 7;
    int g = base_g[b] + (i - base_l[b]);
    if (g < BCAP) {
      part[(size_t)b * BCAP + g] = v;
    } else {
      int p = atomicAdd(ovf_cnt, 1);
      if (p < OVF_CAP) { ovf[2 * p] = (int)(v & 0xffffu); ovf[2 * p + 1] = (int)(v >> 16); }
    }
  }
}

// ---------------- phase 2: per-bucket ELL build, SRC-RADIX slots ----------
// Edge placed at slot ~ src*64/N (CAS probe on collision) -> per-row slot
// order ~ ascending src. Stable compact then dummy-pad (index N -> zero row).
__global__ __launch_bounds__(256) void k_fill2(const unsigned int* __restrict__ part,
                                               const int* __restrict__ cursor,
                                               unsigned short* __restrict__ col,
                                               int* __restrict__ cnt,
                                               float* __restrict__ dinv,
                                               int* __restrict__ ovf_cnt,
                                               int* __restrict__ ovf, int N) {
  __shared__ unsigned int islab[128 * 65];   // 33 KB, stride 65 -> bank spread
  __shared__ int cl[128];
  const int tid = threadIdx.x;
  const int b = blockIdx.x;
  if (tid < 128) cl[tid] = 0;
  for (int i = tid; i < 128 * 65; i += 256) islab[i] = SENT;
  __syncthreads();
  const unsigned int Msc = ((unsigned int)64 << 16) / (unsigned int)N;
  int count = cursor[b]; if (count > BCAP) count = BCAP;
  const unsigned int* p = part + (size_t)b * BCAP;
  for (int i = tid; i < count; i += 256) {
    unsigned int v = p[i];
    int row = (v >> 16) & 127;
    unsigned int s16 = v & 0xffffu;
    int k = atomicAdd(&cl[row], 1);
    if (k < ELL_STRIDE) {
      int s = (int)((s16 * Msc) >> 16);            // 0..63
      unsigned int* base = islab + row * 65;
      while (atomicCAS(&base[s], SENT, s16) != SENT) s = (s + 1) & 63;
    } else {
      int q = atomicAdd(ovf_cnt, 1);
      if (q < OVF_CAP) { ovf[2 * q] = (int)s16; ovf[2 * q + 1] = (int)(v >> 16); }
    }
  }
  __syncthreads();
  if (tid < 128) {   // stable in-place compact; tail = dummy index N
    unsigned int* base = islab + tid * 65;
    int w = 0;
    for (int j = 0; j < 64; ++j) {
      unsigned int v = base[j];
      if (v != SENT) base[w++] = v;
    }
    for (int j = w; j < 64; ++j) base[j] = (unsigned int)N;
  }
  __syncthreads();
  uint4* d4 = (uint4*)(col + (size_t)b * 128 * ELL_STRIDE);
  for (int idx = tid; idx < 128 * 8; idx += 256) {
    int node = idx >> 3, grp = idx & 7;
    const unsigned int* bp = islab + node * 65 + grp * 8;
    uint4 o;
    o.x = (bp[0] & 0xffffu) | (bp[1] << 16);
    o.y = (bp[2] & 0xffffu) | (bp[3] << 16);
    o.z = (bp[4] & 0xffffu) | (bp[5] << 16);
    o.w = (bp[6] & 0xffffu) | (bp[7] << 16);
    d4[idx] = o;
  }
  if (tid < 128) {
    int node = b * 128 + tid;
    if (node < N) {
      int c = cl[tid];
      cnt[node] = c;
      dinv[node] = rsqrtf((float)c + 1.0f);
    }
  }
}

// ---------------- MFMA GEMM -> superchunk-major hb [2][M+1][64ch] ----------
// 512-thread block = 8 waves x 16-row strips = 128 rows. Whole WT staged in
// LDS once (rows padded +8 shorts), single barrier, then straight MFMA.
template <int K, bool AF32>
__global__ __launch_bounds__(512) void k_gemm_mfma(const void* __restrict__ Xv,
                                                   const unsigned short* __restrict__ WT,
                                                   const float* __restrict__ dinv,
                                                   unsigned short* __restrict__ hb,
                                                   int M) {
  constexpr int KP = K + 8;
  __shared__ unsigned short Bs[128 * KP];
  const int tid = threadIdx.x;
  const int wave = tid >> 6, lane = tid & 63;
  const int q = lane >> 4, m = lane & 15;
  const int row0 = blockIdx.x * 128 + wave * 16;   // M % 16 == 0
  const bool active = row0 < M;
  const int arow = row0 + m;

  for (int c = tid; c < 128 * (K / 8); c += 512) {
    int r = c / (K / 8), ko = (c % (K / 8)) * 8;
    *(uint4*)(Bs + r * KP + ko) = *(const uint4*)(WT + (size_t)r * K + ko);
  }

  bf16x8 af[K / 32];
  if (active) {
    #pragma unroll
    for (int ks = 0; ks < K / 32; ++ks) {
      const int k0 = ks * 32 + q * 8;
      if (AF32) {
        const float* X = (const float*)Xv;
        float4 a0 = *(const float4*)(X + (size_t)arow * K + k0);
        float4 a1 = *(const float4*)(X + (size_t)arow * K + k0 + 4);
        af[ks] = (bf16x8){(short)f2bf(a0.x), (short)f2bf(a0.y),
                          (short)f2bf(a0.z), (short)f2bf(a0.w),
                          (short)f2bf(a1.x), (short)f2bf(a1.y),
                          (short)f2bf(a1.z), (short)f2bf(a1.w)};
      } else {
        af[ks] = *(const bf16x8*)((const unsigned short*)Xv +
                                  (size_t)arow * K + k0);
      }
    }
  }
  __syncthreads();
  if (!active) return;

  floatx4 acc[8];
  #pragma unroll
  for (int nt = 0; nt < 8; ++nt) acc[nt] = (floatx4){0.f, 0.f, 0.f, 0.f};
  #pragma unroll
  for (int ks = 0; ks < K / 32; ++ks) {
    const int k0 = ks * 32 + q * 8;
    #pragma unroll
    for (int nt = 0; nt < 8; ++nt) {
      bf16x8 bf = *(const bf16x8*)(Bs + (nt * 16 + m) * KP + k0);
      acc[nt] = __builtin_amdgcn_mfma_f32_16x16x32_bf16(af[ks], bf, acc[nt], 0, 0, 0);
    }
  }
  #pragma unroll
  for (int r = 0; r < 4; ++r) {
    int grow = row0 + q * 4 + r;
    float di = dinv[grow];
    #pragma unroll
    for (int nt = 0; nt < 8; ++nt)
      hb[(size_t)(nt >> 2) * (M + 1) * 64 + (size_t)grow * 64 +
         (nt & 3) * 16 + m] = f2bf(acc[nt][r] * di);
  }
}

// ---------------- 2-superchunk ELL aggregate + bias + ReLU ----------------
// chunk = blockIdx&1 (64 channels); block = 32 nodes (4 waves x 8 nodes).
// 8 lanes per node x dwordx4 = 128B row (2 adjacent 64B lines) -> one VMEM
// instr gathers 8 edges at 128B granularity. Cols in LDS (72-short padded
// rows). No guards: ELL slots >= deg hold dummy node N whose hb row is zero.
template <bool BF16OUT>
__global__ __launch_bounds__(256) void k_agg(const uint4* __restrict__ hb4,
                                             const int* __restrict__ cnt,
                                             const unsigned short* __restrict__ col,
                                             const float* __restrict__ dinv,
                                             const int* __restrict__ ovf_cnt,
                                             const int* __restrict__ ovf,
                                             const float* __restrict__ bias,
                                             void* __restrict__ outv, int n) {
  __shared__ unsigned short cols[32][72];   // padded rows
  const int tid = threadIdx.x;
  const int chunk = blockIdx.x & 1;
  const int nd0 = (blockIdx.x >> 1) * 32;
  {  // preload 32 x 64 cols (dummy-filled for OOB nodes): 1 uint4/thread
    unsigned int dpk = ((unsigned int)n << 16) | (unsigned int)n;
    int node = tid >> 3, off = (tid & 7) * 8;
    uint4 v0 = make_uint4(dpk, dpk, dpk, dpk);
    if (nd0 + node < n)
      v0 = *(const uint4*)(col + (size_t)(nd0 + node) * ELL_STRIDE + off);
    *(uint4*)&cols[node][off] = v0;
  }
  __syncthreads();
  const int wave = tid >> 6, lane = tid & 63;
  const int nodeL = wave * 8 + (lane >> 3);
  const int q = lane & 7;                   // uint4 (8ch) within 64-ch chunk
  const int d = nd0 + nodeL;
  const bool valid = d < n;
  const uint4* slab = hb4 + (size_t)chunk * (n + 1) * 8;
  const unsigned short* lc = cols[nodeL];

  float a0 = 0.f, a1 = 0.f, a2 = 0.f, a3 = 0.f;
  float a4 = 0.f, a5 = 0.f, a6 = 0.f, a7 = 0.f;
#define ADDP(P)                                                            \
  {                                                                        \
    float2 x0 = bfpair((P).x), x1 = bfpair((P).y);                         \
    float2 x2 = bfpair((P).z), x3 = bfpair((P).w);                         \
    a0 += x0.x; a1 += x0.y; a2 += x1.x; a3 += x1.y;                        \
    a4 += x2.x; a5 += x2.y; a6 += x3.x; a7 += x3.y;                        \
  }
  if (valid) {   // self-loop: hb pre-scaled by dinv -> hb[d]*dinv[d]
    uint4 p = slab[(size_t)d * 8 + q];
    ADDP(p)
  }
  int m = valid ? cnt[d] : 0; if (m > ELL_STRIDE) m = ELL_STRIDE;
  int mmax = m;
  #pragma unroll
  for (int s = 8; s < 64; s <<= 1) {
    int o = __shfl_xor(mmax, s);
    mmax = o > mmax ? o : mmax;
  }
  for (int k = 0; k < mmax; k += 8) {
    ushort4 ca = *(const ushort4*)(lc + k);
    ushort4 cb = *(const ushort4*)(lc + k + 4);
    uint4 p0 = slab[(size_t)ca.x * 8 + q];
    uint4 p1 = slab[(size_t)ca.y * 8 + q];
    uint4 p2 = slab[(size_t)ca.z * 8 + q];
    uint4 p3 = slab[(size_t)ca.w * 8 + q];
    uint4 p4 = slab[(size_t)cb.x * 8 + q];
    uint4 p5 = slab[(size_t)cb.y * 8 + q];
    uint4 p6 = slab[(size_t)cb.z * 8 + q];
    uint4 p7 = slab[(size_t)cb.w * 8 + q];
    ADDP(p0) ADDP(p1) ADDP(p2) ADDP(p3)
    ADDP(p4) ADDP(p5) ADDP(p6) ADDP(p7)
  }
  if (valid) {
    int V = *ovf_cnt; if (V > OVF_CAP) V = OVF_CAP;
    for (int j = 0; j < V; ++j) {
      if (ovf[2 * j + 1] == d) {
        uint4 p = slab[(size_t)ovf[2 * j] * 8 + q];
        ADDP(p)
      }
    }
  }
#undef ADDP
  if (!valid) return;
  float di = dinv[d];
  float4 b0 = *(const float4*)(bias + chunk * 64 + q * 8);
  float4 b1 = *(const float4*)(bias + chunk * 64 + q * 8 + 4);
  float r0 = fmaxf(di * a0 + b0.x, 0.f);
  float r1 = fmaxf(di * a1 + b0.y, 0.f);
  float r2 = fmaxf(di * a2 + b0.z, 0.f);
  float r3 = fmaxf(di * a3 + b0.w, 0.f);
  float r4 = fmaxf(di * a4 + b1.x, 0.f);
  float r5 = fmaxf(di * a5 + b1.y, 0.f);
  float r6 = fmaxf(di * a6 + b1.z, 0.f);
  float r7 = fmaxf(di * a7 + b1.w, 0.f);
  if (BF16OUT) {   // row-major [N][128] bf16 (true channel order) for gemm2
    uint4 pk;
    pk.x = (unsigned int)f2bf(r0) | ((unsigned int)f2bf(r1) << 16);
    pk.y = (unsigned int)f2bf(r2) | ((unsigned int)f2bf(r3) << 16);
    pk.z = (unsigned int)f2bf(r4) | ((unsigned int)f2bf(r5) << 16);
    pk.w = (unsigned int)f2bf(r6) | ((unsigned int)f2bf(r7) << 16);
    ((uint4*)outv)[(size_t)d * 16 + chunk * 8 + q] = pk;
  } else {
    float* o = (float*)outv + (size_t)d * 128 + chunk * 64 + q * 8;
    *(float4*)o = make_float4(r0, r1, r2, r3);
    *(float4*)(o + 4) = make_float4(r4, r5, r6, r7);
  }
}

// ---------------------------------------------------------------------------
extern "C" void kernel_launch(void* const* d_in, const int* in_sizes, int n_in,
                              void* d_out, int out_size, void* d_ws, size_t ws_size,
                              hipStream_t stream) {
  const float* x  = (const float*)d_in[0];
  const int*   ei = (const int*)d_in[1];
  const float* W1 = (const float*)d_in[2];
  const float* b1 = (const float*)d_in[3];
  const float* W2 = (const float*)d_in[4];
  const float* b2 = (const float*)d_in[5];
  float* out = (float*)d_out;

  const int IN_CH = 256;
  const int N = in_sizes[0] / IN_CH;   // 50000
  const int E = in_sizes[1] / 2;       // 1,600,000
  const int NB = (N + 127) >> 7;       // 391 buckets

  const int* src = ei;
  const int* dst = ei + E;

  char* ws = (char*)d_ws;
  size_t off = 0;
  auto carve = [&](size_t bytes) {
    void* p = ws + off;
    off += (bytes + 255) & ~(size_t)255;
    return p;
  };
  int*            cursor  = (int*)carve((size_t)NB * 4);
  int*            ovf_cnt = (int*)carve(4);
  int*            ovf     = (int*)carve((size_t)OVF_CAP * 2 * 4);
  int*            cnt     = (int*)carve((size_t)N * 4);
  float*          dinv    = (float*)carve((size_t)N * 4);
  unsigned short* col     = (unsigned short*)carve((size_t)N * ELL_STRIDE * 2); // 6.4MB
  unsigned short* hb      = (unsigned short*)carve((size_t)(N + 1) * 256);      // [2][N+1][64]
  unsigned short* WT1     = (unsigned short*)carve(128 * 256 * 2);
  unsigned short* WT2     = (unsigned short*)carve(128 * 128 * 2);
  // union: part (dead after k_fill2) aliases aggbuf (bf16, by k_agg#1)
  char*           unionp  = (char*)carve((size_t)NB * BCAP * 4);   // 12.8MB
  unsigned int*   part    = (unsigned int*)unionp;
  unsigned short* aggbuf  = (unsigned short*)unionp;               // [N][128] bf16

  k_cvt_w<<<(128 * 256 + 128 * 128 + 255) / 256, 256, 0, stream>>>(
      W1, W2, WT1, WT2, cursor, ovf_cnt, hb, N, NB);
  k_part <<<(E + PART_T - 1) / PART_T, 256, 0, stream>>>(src, dst, cursor, part,
                                                         ovf_cnt, ovf, E, NB);
  k_fill2<<<NB, 256, 0, stream>>>(part, cursor, col, cnt, dinv, ovf_cnt, ovf, N);

  int gblocks = (N + 127) / 128;         // 391
  int ablocks = 2 * ((N + 31) / 32);     // 2 superchunks x 1563
  k_gemm_mfma<256, true ><<<gblocks, 512, 0, stream>>>(x, WT1, dinv, hb, N);
  k_agg<true ><<<ablocks, 256, 0, stream>>>((const uint4*)hb, cnt, col, dinv,
                                            ovf_cnt, ovf, b1, aggbuf, N);
  k_gemm_mfma<128, false><<<gblocks, 512, 0, stream>>>(aggbuf, WT2, dinv, hb, N);
  k_agg<false><<<ablocks, 256, 0, stream>>>((const uint4*)hb, cnt, col, dinv,
                                            ovf_cnt, ovf, b2, out, N);
}

// Round 10
// 226.951 us; speedup vs baseline: 1.0964x; 1.0429x over previous
//
#include <hip/hip_runtime.h>
#include <cstdint>
#include <cstddef>

// ---------------------------------------------------------------------------
// 2-layer GCN, round 24: byte-exact revert to r21 — the measured session best
// (227.8us). r21's two confirmed k_agg terms are jointly maximal:
//  * 128B gather segments (r21: 64->128B = -8.5us total; r22's 256B rows
//    forced a 12.8MB shared slab and regressed +21us),
//  * chunk->XCD affinity (2 superchunks x parity; 6.4MB/XCD).
// Falsified levers: ILP (r15), NT hints (r16/r19), warming (r17), batch
// count (r18), access ordering (r23). Remaining budget: ~84us harness
// poison + ~74us k_agg at the L2 random-segment ceiling + ~70us middle.
// hb layout: [2 superchunks][N+1][64ch] bf16; row N zero (dummy).
//   k_cvt_w: zero cursor/ovf_cnt + dummy hb rows + W1,W2 -> bf16 WT[N][K]
//   k_part / k_fill2: ELL-64 build (fill2 inits slab to dummy index N)
//   k_gemm_mfma<256,AF32>: hb = bf16((x@W1)*dinv[row]) superchunk-major
//   k_agg<BF16OUT=1> -> aggbuf row-major bf16; k_gemm_mfma<128>; k_agg<0>
// ---------------------------------------------------------------------------

#define ELL_STRIDE 64
#define BCAP 8192
#define OVF_CAP 1024
#define PART_T 2048

typedef __attribute__((ext_vector_type(8))) short bf16x8;
typedef __attribute__((ext_vector_type(4))) float floatx4;

__device__ __forceinline__ unsigned short f2bf(float f) {
  unsigned int u = __float_as_uint(f);
  unsigned int r = (u + 0x7fffu + ((u >> 16) & 1u)) >> 16;   // RNE
  return (unsigned short)r;
}
__device__ __forceinline__ float2 bfpair(unsigned int p) {
  float2 r;
  r.x = __uint_as_float(p << 16);
  r.y = __uint_as_float(p & 0xffff0000u);
  return r;
}

// -------- zero workspace + dummy hb rows + W -> bf16 transposed [128][K] ---
__global__ __launch_bounds__(256) void k_cvt_w(const float* __restrict__ W1,
                                               const float* __restrict__ W2,
                                               unsigned short* __restrict__ WT1,
                                               unsigned short* __restrict__ WT2,
                                               int* __restrict__ cursor,
                                               int* __restrict__ ovf_cnt,
                                               unsigned short* __restrict__ hb,
                                               int N, int NB) {
  int i = blockIdx.x * 256 + threadIdx.x;
  if (i < NB) cursor[i] = 0;
  if (i == NB) *ovf_cnt = 0;
  if (i < 128) {   // zero dummy row N of each superchunk: 2 x 64 shorts
    int chunk = i >> 6, j = i & 63;
    hb[(size_t)chunk * (N + 1) * 64 + (size_t)N * 64 + j] = 0;
  }
  if (i < 128 * 256) {                 // WT1[n][k] = W1[k][n], K=256
    int n = i >> 8, k = i & 255;
    WT1[i] = f2bf(W1[k * 128 + n]);
  } else if (i < 128 * 256 + 128 * 128) {
    int j = i - 128 * 256;             // WT2[n][k] = W2[k][n], K=128
    int n = j >> 7, k = j & 127;
    WT2[j] = f2bf(W2[k * 128 + n]);
  }
}

// ---------------- phase 1: bucket partition ----------------
__global__ __launch_bounds__(256) void k_part(const int* __restrict__ src,
                                              const int* __restrict__ dst,
                                              int* __restrict__ cursor,
                                              unsigned int* __restrict__ part,
                                              int* __restrict__ ovf_cnt,
                                              int* __restrict__ ovf,
                                              int E, int NB) {
  __shared__ unsigned int stage1[PART_T];
  __shared__ unsigned int stage2[PART_T];
  __shared__ int hist[512];
  __shared__ int base_g[512];
  __shared__ int base_l[512];
  __shared__ int cl[512];
  __shared__ int sc[256];
  const int tid = threadIdx.x;
  const int e0 = blockIdx.x * PART_T;
  int valid = E - e0; if (valid > PART_T) valid = PART_T;

  hist[tid] = 0; hist[tid + 256] = 0;
  cl[tid] = 0; cl[tid + 256] = 0;
  __syncthreads();
  for (int i = tid; i < valid; i += 256) {
    int e = e0 + i;
    unsigned int v = (unsigned int)(src[e] & 0xffff) | ((unsigned int)dst[e] << 16);
    stage1[i] = v;
    atomicAdd(&hist[(v >> 16) >> 7], 1);
  }
  __syncthreads();
  for (int b = tid; b < NB; b += 256) base_g[b] = atomicAdd(&cursor[b], hist[b]);
  int h0 = hist[2 * tid], h1 = hist[2 * tid + 1];
  int pv = h0 + h1;
  sc[tid] = pv;
  __syncthreads();
  #pragma unroll
  for (int off = 1; off < 256; off <<= 1) {
    int t = (tid >= off) ? sc[tid - off] : 0;
    __syncthreads();
    sc[tid] += t;
    __syncthreads();
  }
  int excl = sc[tid] - pv;
  base_l[2 * tid] = excl;
  base_l[2 * tid + 1] = excl + h0;
  __syncthreads();
  for (int i = tid; i < valid; i += 256) {
    unsigned int v = stage1[i];
    int b = (v >> 16) >> 7;
    int pos = base_l[b] + atomicAdd(&cl[b], 1);
    stage2[pos] = v;
  }
  __syncthreads();
  for (int i = tid; i < valid; i += 256) {
    unsigned int v = stage2[i];
    int b = (v >> 16) >> 7;
    int g = base_g[b] + (i - base_l[b]);
    if (g < BCAP) {
      part[(size_t)b * BCAP + g] = v;
    } else {
      int p = atomicAdd(ovf_cnt, 1);
      if (p < OVF_CAP) { ovf[2 * p] = (int)(v & 0xffffu); ovf[2 * p + 1] = (int)(v >> 16); }
    }
  }
}

// ---------------- phase 2: per-bucket ELL build in LDS ----------------
// slab pre-initialized to dummy index N -> unfilled slots gather a zero row.
__global__ __launch_bounds__(256) void k_fill2(const unsigned int* __restrict__ part,
                                               const int* __restrict__ cursor,
                                               unsigned short* __restrict__ col,
                                               int* __restrict__ cnt,
                                               float* __restrict__ dinv,
                                               int* __restrict__ ovf_cnt,
                                               int* __restrict__ ovf, int N) {
  __shared__ unsigned short slab[128 * ELL_STRIDE];  // 16 KB
  __shared__ int cl[128];
  const int tid = threadIdx.x;
  const int b = blockIdx.x;
  if (tid < 128) cl[tid] = 0;
  {
    unsigned int dpk = ((unsigned int)N << 16) | (unsigned int)N;
    unsigned int* s32 = (unsigned int*)slab;
    #pragma unroll
    for (int i = 0; i < (128 * ELL_STRIDE / 2) / 256; ++i)
      s32[i * 256 + tid] = dpk;
  }
  __syncthreads();
  int count = cursor[b]; if (count > BCAP) count = BCAP;
  const unsigned int* p = part + (size_t)b * BCAP;
  for (int i = tid; i < count; i += 256) {
    unsigned int v = p[i];
    int row = (v >> 16) & 127;
    int k = atomicAdd(&cl[row], 1);
    if (k < ELL_STRIDE) {
      slab[row * ELL_STRIDE + k] = (unsigned short)(v & 0xffffu);
    } else {
      int q = atomicAdd(ovf_cnt, 1);
      if (q < OVF_CAP) { ovf[2 * q] = (int)(v & 0xffffu); ovf[2 * q + 1] = (int)(v >> 16); }
    }
  }
  __syncthreads();
  uint4* d4 = (uint4*)(col + (size_t)b * 128 * ELL_STRIDE);
  const uint4* s4 = (const uint4*)slab;
  #pragma unroll
  for (int i = 0; i < (128 * ELL_STRIDE * 2) / (16 * 256); ++i)
    d4[i * 256 + tid] = s4[i * 256 + tid];
  if (tid < 128) {
    int node = b * 128 + tid;
    if (node < N) {
      int c = cl[tid];
      cnt[node] = c;
      dinv[node] = rsqrtf((float)c + 1.0f);
    }
  }
}

// ---------------- MFMA GEMM -> superchunk-major hb [2][M+1][64ch] ----------
// 512-thread block = 8 waves x 16-row strips = 128 rows. Whole WT staged in
// LDS once (rows padded +8 shorts), single barrier, then straight MFMA.
template <int K, bool AF32>
__global__ __launch_bounds__(512) void k_gemm_mfma(const void* __restrict__ Xv,
                                                   const unsigned short* __restrict__ WT,
                                                   const float* __restrict__ dinv,
                                                   unsigned short* __restrict__ hb,
                                                   int M) {
  constexpr int KP = K + 8;
  __shared__ unsigned short Bs[128 * KP];
  const int tid = threadIdx.x;
  const int wave = tid >> 6, lane = tid & 63;
  const int q = lane >> 4, m = lane & 15;
  const int row0 = blockIdx.x * 128 + wave * 16;   // M % 16 == 0
  const bool active = row0 < M;
  const int arow = row0 + m;

  for (int c = tid; c < 128 * (K / 8); c += 512) {
    int r = c / (K / 8), ko = (c % (K / 8)) * 8;
    *(uint4*)(Bs + r * KP + ko) = *(const uint4*)(WT + (size_t)r * K + ko);
  }

  bf16x8 af[K / 32];
  if (active) {
    #pragma unroll
    for (int ks = 0; ks < K / 32; ++ks) {
      const int k0 = ks * 32 + q * 8;
      if (AF32) {
        const float* X = (const float*)Xv;
        float4 a0 = *(const float4*)(X + (size_t)arow * K + k0);
        float4 a1 = *(const float4*)(X + (size_t)arow * K + k0 + 4);
        af[ks] = (bf16x8){(short)f2bf(a0.x), (short)f2bf(a0.y),
                          (short)f2bf(a0.z), (short)f2bf(a0.w),
                          (short)f2bf(a1.x), (short)f2bf(a1.y),
                          (short)f2bf(a1.z), (short)f2bf(a1.w)};
      } else {
        af[ks] = *(const bf16x8*)((const unsigned short*)Xv +
                                  (size_t)arow * K + k0);
      }
    }
  }
  __syncthreads();
  if (!active) return;

  floatx4 acc[8];
  #pragma unroll
  for (int nt = 0; nt < 8; ++nt) acc[nt] = (floatx4){0.f, 0.f, 0.f, 0.f};
  #pragma unroll
  for (int ks = 0; ks < K / 32; ++ks) {
    const int k0 = ks * 32 + q * 8;
    #pragma unroll
    for (int nt = 0; nt < 8; ++nt) {
      bf16x8 bf = *(const bf16x8*)(Bs + (nt * 16 + m) * KP + k0);
      acc[nt] = __builtin_amdgcn_mfma_f32_16x16x32_bf16(af[ks], bf, acc[nt], 0, 0, 0);
    }
  }
  #pragma unroll
  for (int r = 0; r < 4; ++r) {
    int grow = row0 + q * 4 + r;
    float di = dinv[grow];
    #pragma unroll
    for (int nt = 0; nt < 8; ++nt)
      hb[(size_t)(nt >> 2) * (M + 1) * 64 + (size_t)grow * 64 +
         (nt & 3) * 16 + m] = f2bf(acc[nt][r] * di);
  }
}

// ---------------- 2-superchunk ELL aggregate + bias + ReLU ----------------
// chunk = blockIdx&1 (64 channels); block = 32 nodes (4 waves x 8 nodes).
// 8 lanes per node x dwordx4 = 128B row (2 adjacent 64B lines) -> one VMEM
// instr gathers 8 edges at 128B granularity. Cols in LDS (72-short padded
// rows). No guards: ELL slots >= deg hold dummy node N whose hb row is zero.
template <bool BF16OUT>
__global__ __launch_bounds__(256) void k_agg(const uint4* __restrict__ hb4,
                                             const int* __restrict__ cnt,
                                             const unsigned short* __restrict__ col,
                                             const float* __restrict__ dinv,
                                             const int* __restrict__ ovf_cnt,
                                             const int* __restrict__ ovf,
                                             const float* __restrict__ bias,
                                             void* __restrict__ outv, int n) {
  __shared__ unsigned short cols[32][72];   // padded rows
  const int tid = threadIdx.x;
  const int chunk = blockIdx.x & 1;
  const int nd0 = (blockIdx.x >> 1) * 32;
  {  // preload 32 x 64 cols (dummy-filled for OOB nodes): 1 uint4/thread
    unsigned int dpk = ((unsigned int)n << 16) | (unsigned int)n;
    int node = tid >> 3, off = (tid & 7) * 8;
    uint4 v0 = make_uint4(dpk, dpk, dpk, dpk);
    if (nd0 + node < n)
      v0 = *(const uint4*)(col + (size_t)(nd0 + node) * ELL_STRIDE + off);
    *(uint4*)&cols[node][off] = v0;
  }
  __syncthreads();
  const int wave = tid >> 6, lane = tid & 63;
  const int nodeL = wave * 8 + (lane >> 3);
  const int q = lane & 7;                   // uint4 (8ch) within 64-ch chunk
  const int d = nd0 + nodeL;
  const bool valid = d < n;
  const uint4* slab = hb4 + (size_t)chunk * (n + 1) * 8;
  const unsigned short* lc = cols[nodeL];

  float a0 = 0.f, a1 = 0.f, a2 = 0.f, a3 = 0.f;
  float a4 = 0.f, a5 = 0.f, a6 = 0.f, a7 = 0.f;
#define ADDP(P)                                                            \
  {                                                                        \
    float2 x0 = bfpair((P).x), x1 = bfpair((P).y);                         \
    float2 x2 = bfpair((P).z), x3 = bfpair((P).w);                         \
    a0 += x0.x; a1 += x0.y; a2 += x1.x; a3 += x1.y;                        \
    a4 += x2.x; a5 += x2.y; a6 += x3.x; a7 += x3.y;                        \
  }
  if (valid) {   // self-loop: hb pre-scaled by dinv -> hb[d]*dinv[d]
    uint4 p = slab[(size_t)d * 8 + q];
    ADDP(p)
  }
  int m = valid ? cnt[d] : 0; if (m > ELL_STRIDE) m = ELL_STRIDE;
  int mmax = m;
  #pragma unroll
  for (int s = 8; s < 64; s <<= 1) {
    int o = __shfl_xor(mmax, s);
    mmax = o > mmax ? o : mmax;
  }
  for (int k = 0; k < mmax; k += 8) {
    ushort4 ca = *(const ushort4*)(lc + k);
    ushort4 cb = *(const ushort4*)(lc + k + 4);
    uint4 p0 = slab[(size_t)ca.x * 8 + q];
    uint4 p1 = slab[(size_t)ca.y * 8 + q];
    uint4 p2 = slab[(size_t)ca.z * 8 + q];
    uint4 p3 = slab[(size_t)ca.w * 8 + q];
    uint4 p4 = slab[(size_t)cb.x * 8 + q];
    uint4 p5 = slab[(size_t)cb.y * 8 + q];
    uint4 p6 = slab[(size_t)cb.z * 8 + q];
    uint4 p7 = slab[(size_t)cb.w * 8 + q];
    ADDP(p0) ADDP(p1) ADDP(p2) ADDP(p3)
    ADDP(p4) ADDP(p5) ADDP(p6) ADDP(p7)
  }
  if (valid) {
    int V = *ovf_cnt; if (V > OVF_CAP) V = OVF_CAP;
    for (int j = 0; j < V; ++j) {
      if (ovf[2 * j + 1] == d) {
        uint4 p = slab[(size_t)ovf[2 * j] * 8 + q];
        ADDP(p)
      }
    }
  }
#undef ADDP
  if (!valid) return;
  float di = dinv[d];
  float4 b0 = *(const float4*)(bias + chunk * 64 + q * 8);
  float4 b1 = *(const float4*)(bias + chunk * 64 + q * 8 + 4);
  float r0 = fmaxf(di * a0 + b0.x, 0.f);
  float r1 = fmaxf(di * a1 + b0.y, 0.f);
  float r2 = fmaxf(di * a2 + b0.z, 0.f);
  float r3 = fmaxf(di * a3 + b0.w, 0.f);
  float r4 = fmaxf(di * a4 + b1.x, 0.f);
  float r5 = fmaxf(di * a5 + b1.y, 0.f);
  float r6 = fmaxf(di * a6 + b1.z, 0.f);
  float r7 = fmaxf(di * a7 + b1.w, 0.f);
  if (BF16OUT) {   // row-major [N][128] bf16 (true channel order) for gemm2
    uint4 pk;
    pk.x = (unsigned int)f2bf(r0) | ((unsigned int)f2bf(r1) << 16);
    pk.y = (unsigned int)f2bf(r2) | ((unsigned int)f2bf(r3) << 16);
    pk.z = (unsigned int)f2bf(r4) | ((unsigned int)f2bf(r5) << 16);
    pk.w = (unsigned int)f2bf(r6) | ((unsigned int)f2bf(r7) << 16);
    ((uint4*)outv)[(size_t)d * 16 + chunk * 8 + q] = pk;
  } else {
    float* o = (float*)outv + (size_t)d * 128 + chunk * 64 + q * 8;
    *(float4*)o = make_float4(r0, r1, r2, r3);
    *(float4*)(o + 4) = make_float4(r4, r5, r6, r7);
  }
}

// ---------------------------------------------------------------------------
extern "C" void kernel_launch(void* const* d_in, const int* in_sizes, int n_in,
                              void* d_out, int out_size, void* d_ws, size_t ws_size,
                              hipStream_t stream) {
  const float* x  = (const float*)d_in[0];
  const int*   ei = (const int*)d_in[1];
  const float* W1 = (const float*)d_in[2];
  const float* b1 = (const float*)d_in[3];
  const float* W2 = (const float*)d_in[4];
  const float* b2 = (const float*)d_in[5];
  float* out = (float*)d_out;

  const int IN_CH = 256;
  const int N = in_sizes[0] / IN_CH;   // 50000
  const int E = in_sizes[1] / 2;       // 1,600,000
  const int NB = (N + 127) >> 7;       // 391 buckets

  const int* src = ei;
  const int* dst = ei + E;

  char* ws = (char*)d_ws;
  size_t off = 0;
  auto carve = [&](size_t bytes) {
    void* p = ws + off;
    off += (bytes + 255) & ~(size_t)255;
    return p;
  };
  int*            cursor  = (int*)carve((size_t)NB * 4);
  int*            ovf_cnt = (int*)carve(4);
  int*            ovf     = (int*)carve((size_t)OVF_CAP * 2 * 4);
  int*            cnt     = (int*)carve((size_t)N * 4);
  float*          dinv    = (float*)carve((size_t)N * 4);
  unsigned short* col     = (unsigned short*)carve((size_t)N * ELL_STRIDE * 2); // 6.4MB
  unsigned short* hb      = (unsigned short*)carve((size_t)(N + 1) * 256);      // [2][N+1][64]
  unsigned short* WT1     = (unsigned short*)carve(128 * 256 * 2);
  unsigned short* WT2     = (unsigned short*)carve(128 * 128 * 2);
  // union: part (dead after k_fill2) aliases aggbuf (bf16, by k_agg#1)
  char*           unionp  = (char*)carve((size_t)NB * BCAP * 4);   // 12.8MB
  unsigned int*   part    = (unsigned int*)unionp;
  unsigned short* aggbuf  = (unsigned short*)unionp;               // [N][128] bf16

  k_cvt_w<<<(128 * 256 + 128 * 128 + 255) / 256, 256, 0, stream>>>(
      W1, W2, WT1, WT2, cursor, ovf_cnt, hb, N, NB);
  k_part <<<(E + PART_T - 1) / PART_T, 256, 0, stream>>>(src, dst, cursor, part,
                                                         ovf_cnt, ovf, E, NB);
  k_fill2<<<NB, 256, 0, stream>>>(part, cursor, col, cnt, dinv, ovf_cnt, ovf, N);

  int gblocks = (N + 127) / 128;         // 391
  int ablocks = 2 * ((N + 31) / 32);     // 2 superchunks x 1563
  k_gemm_mfma<256, true ><<<gblocks, 512, 0, stream>>>(x, WT1, dinv, hb, N);
  k_agg<true ><<<ablocks, 256, 0, stream>>>((const uint4*)hb, cnt, col, dinv,
                                            ovf_cnt, ovf, b1, aggbuf, N);
  k_gemm_mfma<128, false><<<gblocks, 512, 0, stream>>>(aggbuf, WT2, dinv, hb, N);
  k_agg<false><<<ablocks, 256, 0, stream>>>((const uint4*)hb, cnt, col, dinv,
                                            ovf_cnt, ovf, b2, out, N);
}